// Round 21
// baseline (176.287 us; speedup 1.0000x reference)
//
#include <hip/hip_runtime.h>

#define AS1(p) ((const __attribute__((address_space(1))) void*)(p))
#define AS3(p) ((__attribute__((address_space(3))) void*)(p))

typedef unsigned short u16;
typedef __bf16 bf16x8 __attribute__((ext_vector_type(8)));
typedef short s16x8 __attribute__((ext_vector_type(8)));
typedef float f32x4 __attribute__((ext_vector_type(4)));
typedef unsigned short u16x4 __attribute__((ext_vector_type(4)));
typedef unsigned short u16x8v __attribute__((ext_vector_type(8)));

__device__ __forceinline__ u16 f2bf(float x) {
    unsigned u = __float_as_uint(x);
    unsigned r = (u + 0x7FFFu + ((u >> 16) & 1u)) >> 16;
    return (u16)r;
}

template <typename V8>
__device__ __forceinline__ auto mfma_sel(V8 a, V8 b, f32x4 c, int)
    -> decltype(__builtin_amdgcn_mfma_f32_16x16x32_bf16(a, b, c, 0, 0, 0))
{
    return __builtin_amdgcn_mfma_f32_16x16x32_bf16(a, b, c, 0, 0, 0);
}
template <typename V8>
__device__ __forceinline__ f32x4 mfma_sel(V8 a, V8 b, f32x4 c, long)
{
    s16x8 a2 = __builtin_bit_cast(s16x8, a);
    s16x8 b2 = __builtin_bit_cast(s16x8, b);
    return __builtin_amdgcn_mfma_f32_16x16x32_bf16(a2, b2, c, 0, 0, 0);
}
__device__ __forceinline__ f32x4 mfma16x16x32(bf16x8 a, bf16x8 b, f32x4 c)
{
    return mfma_sel(a, b, c, 0);
}

// ------- unified fp32 -> bf16 convert (x + 4 weights) + rsum zero-fill -------
__global__ __launch_bounds__(256) void cvt_all_kernel(const float* __restrict__ x,
                                                      const float* __restrict__ Wq,
                                                      const float* __restrict__ Wk,
                                                      const float* __restrict__ Wv,
                                                      const float* __restrict__ Wp,
                                                      u16* __restrict__ xb,
                                                      u16* __restrict__ Wcat,
                                                      u16* __restrict__ Wpb,
                                                      float* __restrict__ rsum,
                                                      int n4x, int n4w, int nrs)
{
    int i = blockIdx.x * 256 + threadIdx.x;
    const int total = n4x + 4 * n4w;
    if (i >= total) {
        int j = i - total;
        if (j < nrs) rsum[j] = 0.f;     // zero the row-sum accumulator each call
        return;
    }
    const float* src;
    u16* dst;
    int off;
    if (i < n4x) {
        src = x; dst = xb; off = i;
    } else {
        int j = i - n4x;
        int w = j >> 18;            // n4w == 262144 == 1<<18
        off = j & (n4w - 1);
        src = (w == 0) ? Wq : (w == 1) ? Wk : (w == 2) ? Wv : Wp;
        dst = (w == 3) ? Wpb : (Wcat + (size_t)w * n4w * 4);
    }
    float4 f = ((const float4*)src)[off];
    u16x4 o;
    o.x = f2bf(f.x); o.y = f2bf(f.y); o.z = f2bf(f.z); o.w = f2bf(f.w);
    ((u16x4*)dst)[off] = o;
}

#define MBM 128
#define MBK 64

// ============ m97-structure NT GEMM: 128x128, BK=64, 256 threads ============
// Single-buffered 32 KB static LDS, 2 barriers per K-tile. Scores (EXPOUT/
// FUSET) and PV (RDIV/PACKA). This config is the session argmin, validated
// twice (r16: 175.7, r20: 175.3).
// T2 swizzle (rule 21): linear LDS dest, inverse-XOR'd global SOURCE slot,
// XOR'd read: slot16B ^= (row&7). Conflict-free (r3..r20: 0).
// EXPOUT: scores mode — causal mask + exp(s-16) shift-softmax, P causally
//   PACKED, per-row sums via atomics. RDIV: PV epilogue divides by rsum.
// PACKA: A = packed P (block-row a: lda=128(a+1), base -8192*a*(a+1)).
// FUSET: z==4 plane transposes v (vb[8192][1024] -> vT[1024][8192], ld 8192).
template <int BIAS, int OUTBF16, int CSKIP, int CKB, int SWZ, int MW,
          int EXPOUT, int RDIV, int PACKA, int FUSET>
__global__ __launch_bounds__(256, MW)
void gemm128(const u16* __restrict__ A, const u16* __restrict__ B,
             void* __restrict__ Cv, const float* __restrict__ bias,
             void* __restrict__ C2, const float* __restrict__ bias2,
             void* __restrict__ C3, const float* __restrict__ bias3,
             float* __restrict__ rsum,
             int M, int N, int K, int lda, int ldb, int ldc,
             long long sA, long long sB, long long sC, float scale)
{
    __shared__ u16 lA[MBM * MBK];
    __shared__ u16 lB[MBM * MBK];

    if (FUSET && blockIdx.z == 4) {
        // ---- fused v-transpose: vb[8192][1024] -> vT[1024][8192] ----
        const u16* vin = (const u16*)C2;
        u16* vout = (u16*)C3;
        u16* tl = lA;                       // [64][65] scratch
        const int t = threadIdx.x;
        const int r = t >> 2, c4 = (t & 3) << 4;
        const int bid = blockIdx.y * 16 + blockIdx.x;     // 0..255
        for (int it = 0; it < 8; ++it) {
            const int tile = bid * 8 + it;                // 0..2047
            const int tc0 = (tile & 15) * 64;             // D cols
            const int tr0 = (tile >> 4) * 64;             // M rows (0..8191)
            const u16* src = vin + (size_t)(tr0 + r) * 1024 + tc0 + c4;
            u16x8v a0 = *(const u16x8v*)src;
            u16x8v a1 = *(const u16x8v*)(src + 8);
            #pragma unroll
            for (int j = 0; j < 8; ++j) {
                tl[r * 65 + c4 + j] = a0[j];
                tl[r * 65 + c4 + 8 + j] = a1[j];
            }
            __syncthreads();
            u16x8v b0, b1;
            #pragma unroll
            for (int j = 0; j < 8; ++j) {
                b0[j] = tl[(c4 + j) * 65 + r];
                b1[j] = tl[(c4 + 8 + j) * 65 + r];
            }
            u16* dst = vout + (size_t)(tc0 + r) * 8192 + tr0 + c4;  // ld = FULL M
            *(u16x8v*)dst = b0;
            *(u16x8v*)(dst + 8) = b1;
            __syncthreads();
        }
        return;
    }

    int bx = blockIdx.x, by = blockIdx.y;
    if (SWZ) {
        const int gx = gridDim.x;
        const int nwg = gx * gridDim.y;
        int id = by * gx + bx;
        id = (id & 7) * (nwg >> 3) + (id >> 3);
        bx = id % gx; by = id / gx;
    }
    if (CKB) by = gridDim.y - 1 - by;       // longest-K blocks first
    const int m0 = by * MBM;
    const int n0 = bx * MBM;
    if (CSKIP && n0 > m0 + MBM - 1) return;

    const int z = blockIdx.z;
    const int ablk = m0 >> 7;               // row-block index (packed layouts)
    long long abase = (long long)z * sA;
    int lda_e = lda;
    if (PACKA) {
        lda_e = (ablk + 1) << 7;            // == Keff
        abase -= (long long)8192 * ablk * (ablk + 1);
    }
    const u16* Ab = A + abase;
    B += (size_t)z * (size_t)sB;

    const int t = threadIdx.x;
    const int lane = t & 63;
    const int w = t >> 6;
    const int wr = w >> 1;           // 0..1 (M)
    const int wc = w & 1;            // 0..1 (N)
    const int fr = lane & 15, fg = lane >> 4;

    int Keff = K;
    if (CKB) { Keff = m0 + MBM; if (Keff > K) Keff = K; }
    const int nk = Keff / MBK;

    f32x4 acc[4][4] = {};

    for (int kt = 0; kt < nk; ++kt) {
        const int k0 = kt * MBK;
        #pragma unroll
        for (int i = 0; i < 4; ++i) {
            int c = t + i * 256;
            int row = c >> 3;
            int sl = (c & 7) ^ (row & 7);      // inverse-swizzled source slot
            __builtin_amdgcn_global_load_lds(
                AS1(Ab + (long long)(m0 + row) * lda_e + k0 + sl * 8),
                AS3(&lA[c * 8]), 16, 0, 0);
            __builtin_amdgcn_global_load_lds(
                AS1(B + (size_t)(n0 + row) * ldb + k0 + sl * 8),
                AS3(&lB[c * 8]), 16, 0, 0);
        }
        __syncthreads();                        // drains vmcnt: tile staged

        #pragma unroll
        for (int kk = 0; kk < MBK; kk += 32) {
            const int cs = (kk >> 3) + fg;      // column 16B-slot 0..7
            bf16x8 af[4], bfv[4];
            #pragma unroll
            for (int mi = 0; mi < 4; ++mi) {
                int row = wr * 64 + mi * 16 + fr;
                af[mi] = *(const bf16x8*)&lA[row * 64 + ((cs ^ (row & 7)) << 3)];
            }
            #pragma unroll
            for (int ni = 0; ni < 4; ++ni) {
                int row = wc * 64 + ni * 16 + fr;
                bfv[ni] = *(const bf16x8*)&lB[row * 64 + ((cs ^ (row & 7)) << 3)];
            }
            __builtin_amdgcn_s_setprio(1);
            #pragma unroll
            for (int mi = 0; mi < 4; ++mi)
                #pragma unroll
                for (int ni = 0; ni < 4; ++ni)
                    acc[mi][ni] = mfma16x16x32(af[mi], bfv[ni], acc[mi][ni]);
            __builtin_amdgcn_s_setprio(0);
        }
        __syncthreads();                        // reads done before next stage
    }

    // ---- epilogue: C/D layout col=lane&15, row=(lane>>4)*4+reg ----
    if (EXPOUT) {
        // scores: causal mask + exp(s-16); PACKED C; per-row sum atomics
        const int ldcp = (ablk + 1) << 7;
        u16* Cp = (u16*)Cv + ((long long)z * sC - (long long)8192 * ablk * (ablk + 1));
        float prs[4][4];
        #pragma unroll
        for (int mi = 0; mi < 4; ++mi)
            #pragma unroll
            for (int j = 0; j < 4; ++j) prs[mi][j] = 0.f;
        #pragma unroll
        for (int mi = 0; mi < 4; ++mi) {
            int row0 = m0 + wr * 64 + mi * 16 + fg * 4;
            #pragma unroll
            for (int ni = 0; ni < 4; ++ni) {
                int col = n0 + wc * 64 + ni * 16 + fr;
                #pragma unroll
                for (int j = 0; j < 4; ++j) {
                    int row = row0 + j;
                    float p = (col <= row) ? __expf(acc[mi][ni][j] - 16.f) : 0.f;
                    Cp[(long long)row * ldcp + col] = f2bf(p);
                    prs[mi][j] += p;
                }
            }
        }
        #pragma unroll
        for (int mi = 0; mi < 4; ++mi) {
            #pragma unroll
            for (int j = 0; j < 4; ++j) {
                float s = prs[mi][j];
                s += __shfl_xor(s, 1); s += __shfl_xor(s, 2);
                s += __shfl_xor(s, 4); s += __shfl_xor(s, 8);
                if (fr == 0)
                    atomicAdd(&rsum[(size_t)z * M + m0 + wr * 64 + mi * 16 + fg * 4 + j], s);
            }
        }
        return;
    }

    #pragma unroll
    for (int mi = 0; mi < 4; ++mi) {
        int row0 = m0 + wr * 64 + mi * 16 + fg * 4;
        float invr[4];
        if (RDIV) {
            #pragma unroll
            for (int j = 0; j < 4; ++j)
                invr[j] = 1.f / rsum[(size_t)z * M + row0 + j];
        }
        #pragma unroll
        for (int ni = 0; ni < 4; ++ni) {
            int col = n0 + wc * 64 + ni * 16 + fr;
            float bval = (BIAS == 1) ? bias[col] : 0.f;
            #pragma unroll
            for (int j = 0; j < 4; ++j) {
                float v = RDIV ? acc[mi][ni][j] * invr[j]
                               : (acc[mi][ni][j] + bval) * scale;
                size_t off = (size_t)z * (size_t)sC + (size_t)(row0 + j) * ldc + col;
                if (OUTBF16) ((u16*)Cv)[off] = f2bf(v);
                else         ((float*)Cv)[off] = v;
            }
        }
    }
}

// ========== pipelined NT GEMM: counted-vmcnt, A-triple / B-double buffer =====
// 128x128, BK=64, 256 threads, 80 KB dynamic LDS -> 2 blocks/CU.
// QKV (BIAS=3) + proj: best-total config (argmin r16/r20).
// Race proof: writes target bufA[(t+2)%3]==bufA[(t-1)%3], bufB[(t+1)&1]==
// bufB[(t-1)&1], whose ds_reads completed (compiler lgkmcnt before MFMA)
// before barrier(t-1); every wave issues iter-t writes only after that
// barrier. Reads at iter t confirmed by every wave's vmcnt(4) at t-1.
#define PLDS 81920

template <int BIAS, int OUTBF16>
__global__ __launch_bounds__(256, 2)
void gemm128p(const u16* __restrict__ A, const u16* __restrict__ B,
              void* __restrict__ Cv, const float* __restrict__ bias,
              void* __restrict__ C2, const float* __restrict__ bias2,
              void* __restrict__ C3, const float* __restrict__ bias3,
              int M, int N, int K, int lda, int ldb, int ldc, float scale)
{
    extern __shared__ char smem[];

    // bijective XCD swizzle (nwg % 8 == 0 at both call sites)
    const int gx = gridDim.x;
    const int nwg = gx * gridDim.y;
    int id = blockIdx.y * gx + blockIdx.x;
    id = (id & 7) * (nwg >> 3) + (id >> 3);
    const int bx = id % gx;
    const int by = id / gx;
    const int m0 = by * MBM;
    const int n0 = bx * MBM;

    const int t = threadIdx.x;
    const int lane = t & 63;
    const int w = t >> 6;
    const int wr = w >> 1, wc = w & 1;
    const int fr = lane & 15, fg = lane >> 4;

    const int nk = K / MBK;

    char* const aB = smem;           // 3 x 16 KB A buffers
    char* const bB = smem + 49152;   // 2 x 16 KB B buffers

    auto STA = [&](int kt, char* dst) {
        const int k0 = kt * MBK;
        #pragma unroll
        for (int i = 0; i < 4; ++i) {
            int c = t + i * 256;
            int row = c >> 3;
            int sl = (c & 7) ^ (row & 7);
            __builtin_amdgcn_global_load_lds(
                AS1(A + (size_t)(m0 + row) * lda + k0 + sl * 8),
                AS3(dst + c * 16), 16, 0, 0);
        }
    };
    auto STB = [&](int kt, char* dst) {
        const int k0 = kt * MBK;
        #pragma unroll
        for (int i = 0; i < 4; ++i) {
            int c = t + i * 256;
            int row = c >> 3;
            int sl = (c & 7) ^ (row & 7);
            __builtin_amdgcn_global_load_lds(
                AS1(B + (size_t)(n0 + row) * ldb + k0 + sl * 8),
                AS3(dst + c * 16), 16, 0, 0);
        }
    };

    f32x4 acc[4][4] = {};

    // prologue
    STA(0, aB);
    STB(0, bB);
    if (nk > 1) {
        STA(1, aB + 16384);
        asm volatile("s_waitcnt vmcnt(4)" ::: "memory");
    } else {
        asm volatile("s_waitcnt vmcnt(0)" ::: "memory");
    }
    __builtin_amdgcn_s_barrier();

    int ca = 0;                      // A buffer holding tile kt
    for (int kt = 0; kt < nk; ++kt) {
        if (kt + 1 < nk) STB(kt + 1, bB + ((kt + 1) & 1) * 16384);
        int pa = ca + 2; if (pa >= 3) pa -= 3;
        if (kt + 2 < nk) STA(kt + 2, aB + pa * 16384);

        const char* la = aB + ca * 16384;
        const char* lb = bB + (kt & 1) * 16384;
        #pragma unroll
        for (int kk = 0; kk < MBK; kk += 32) {
            const int cs = (kk >> 3) + fg;
            bf16x8 af[4], bfv[4];
            #pragma unroll
            for (int mi = 0; mi < 4; ++mi) {
                int row = wr * 64 + mi * 16 + fr;
                af[mi] = *(const bf16x8*)(la + row * 128 + ((cs ^ (row & 7)) << 4));
            }
            #pragma unroll
            for (int ni = 0; ni < 4; ++ni) {
                int row = wc * 64 + ni * 16 + fr;
                bfv[ni] = *(const bf16x8*)(lb + row * 128 + ((cs ^ (row & 7)) << 4));
            }
            __builtin_amdgcn_s_setprio(1);
            #pragma unroll
            for (int mi = 0; mi < 4; ++mi)
                #pragma unroll
                for (int ni = 0; ni < 4; ++ni)
                    acc[mi][ni] = mfma16x16x32(af[mi], bfv[ni], acc[mi][ni]);
            __builtin_amdgcn_s_setprio(0);
        }

        if (kt + 2 < nk)      asm volatile("s_waitcnt vmcnt(4)" ::: "memory");
        else if (kt + 1 < nk) asm volatile("s_waitcnt vmcnt(0)" ::: "memory");
        if (kt + 1 < nk) __builtin_amdgcn_s_barrier();
        ++ca; if (ca >= 3) ca = 0;
    }

    // ---- epilogue: C/D layout col=lane&15, row=(lane>>4)*4+reg ----
    #pragma unroll
    for (int mi = 0; mi < 4; ++mi) {
        int row0 = m0 + wr * 64 + mi * 16 + fg * 4;
        #pragma unroll
        for (int ni = 0; ni < 4; ++ni) {
            int col = n0 + wc * 64 + ni * 16 + fr;
            if (BIAS == 3) {
                int seg = col >> 10;
                int ccol = col & 1023;
                u16* dst = (seg == 0) ? (u16*)Cv : (seg == 1) ? (u16*)C2 : (u16*)C3;
                float b = ((seg == 0) ? bias : (seg == 1) ? bias2 : bias3)[ccol];
                float sc_ = (seg == 0) ? scale : 1.f;
                #pragma unroll
                for (int j = 0; j < 4; ++j)
                    dst[(size_t)(row0 + j) * 1024 + ccol] =
                        f2bf((acc[mi][ni][j] + b) * sc_);
            } else {
                float bval = (BIAS == 1) ? bias[col] : 0.f;
                #pragma unroll
                for (int j = 0; j < 4; ++j) {
                    float v = (acc[mi][ni][j] + bval) * scale;
                    size_t off = (size_t)(row0 + j) * ldc + col;
                    if (OUTBF16) ((u16*)Cv)[off] = f2bf(v);
                    else         ((float*)Cv)[off] = v;
                }
            }
        }
    }
}

// ---------------- host launcher ----------------
// ws layout (87.1 MB; ws >= 92.3 MB deduced from r1):
//   [xb 16.78M | Wpb 2.1M | qb 16.78M | kb 16.78M | rsum 32K | vb 16.78M |
//    scp 17.83M (packed P; first 6.29M overlaid by Wcat, dead after QKV)]
//   vTb aliases xb (x dead after QKV; written by fused transpose during the
//   scores launch). attnb aliases kb (kb dead after scores).
extern "C" void kernel_launch(void* const* d_in, const int* in_sizes, int n_in,
                              void* d_out, int out_size, void* d_ws, size_t ws_size,
                              hipStream_t stream)
{
    (void)in_sizes; (void)n_in; (void)out_size; (void)ws_size;
    const float* x  = (const float*)d_in[0];
    const float* Wq = (const float*)d_in[1];
    const float* bq = (const float*)d_in[2];
    const float* Wk = (const float*)d_in[3];
    const float* bk = (const float*)d_in[4];
    const float* Wv = (const float*)d_in[5];
    const float* bv = (const float*)d_in[6];
    const float* Wp = (const float*)d_in[7];
    const float* bp = (const float*)d_in[8];

    const int D = 1024, S = 2048, B = 4;
    const int M = B * S; // 8192
    const long long sP = 16384LL * 136;     // packed P elems per batch

    char* p = (char*)d_ws;
    u16* xb    = (u16*)p; p += (size_t)M * D * 2;      // 16.78M
    u16* Wpb   = (u16*)p; p += (size_t)D * D * 2;      // 2.1M
    u16* qb    = (u16*)p; p += (size_t)M * D * 2;      // 16.78M
    u16* kb    = (u16*)p; p += (size_t)M * D * 2;      // 16.78M
    float* rsum = (float*)p; p += (size_t)B * S * 4;   // 32K
    u16* vb    = (u16*)p; p += (size_t)M * D * 2;      // 16.78M
    u16* scp   = (u16*)p;                              // packed P 17.83M
    u16* Wcat  = scp;                                  // overlay: dead after QKV
    u16* vTb   = xb;                                   // alias: x dead after QKV
    u16* attnb = kb;                                   // alias: kb dead after scores

    const int n4x = M * D / 4;      // 2097152
    const int n4w = D * D / 4;      // 262144
    const int nrs = B * S;          // 8192

    hipFuncSetAttribute((const void*)gemm128p<3, 1>,
                        hipFuncAttributeMaxDynamicSharedMemorySize, PLDS);
    hipFuncSetAttribute((const void*)gemm128p<1, 0>,
                        hipFuncAttributeMaxDynamicSharedMemorySize, PLDS);

    // fp32 -> bf16 (x + weights) + rsum zero-fill, one launch
    cvt_all_kernel<<<(n4x + 4 * n4w + nrs + 255) / 256, 256, 0, stream>>>(
        x, Wq, Wk, Wv, Wp, xb, Wcat, Wpb, rsum, n4x, n4w, nrs);

    // fused QKV: [q|k|v] = x Wcat^T + biases (q scaled); PIPELINED kernel
    gemm128p<3, 1><<<dim3(3 * D / MBM, M / MBM), 256, PLDS, stream>>>(
        xb, Wcat, qb, bq, kb, bk, vb, bv,
        M, 3 * D, D, D, D, D, 0.03125f);

    // scores -> packed P = exp(s-16), causal mask, row-sum atomics (EXPOUT);
    // z==4 plane: fused v-transpose (vb -> vTb) riding idle causal-skip slots
    gemm128<0, 1, 1, 0, 0, 4, 1, 0, 0, 1><<<dim3(S / MBM, S / MBM, B + 1), 256, 0, stream>>>(
        qb, kb, scp, nullptr, vb, nullptr, vTb, nullptr, rsum,
        S, S, D, D, D, 0,
        (long long)S * D, (long long)S * D, sP, 1.0f);

    // attn_out = (P v) / rsum[row]  (RDIV; PACKA; K causally bounded)
    gemm128<0, 1, 0, 1, 0, 4, 0, 1, 1, 0><<<dim3(D / MBM, S / MBM, B), 256, 0, stream>>>(
        scp, vTb, attnb, nullptr, nullptr, nullptr, nullptr, nullptr, rsum,
        S, D, S, 0, M, D,
        sP, (long long)S, (long long)S * D, 1.0f);

    // out = attn_out Wp^T + bp  (fp32 output); PIPELINED gemm128p
    gemm128p<1, 0><<<dim3(D / MBM, M / MBM), 256, PLDS, stream>>>(
        attnb, Wpb, d_out, bp, nullptr, nullptr, nullptr, nullptr,
        M, D, D, D, D, D, 1.0f);
}

// Round 22
// 175.134 us; speedup vs baseline: 1.0066x; 1.0066x over previous
//
#include <hip/hip_runtime.h>

#define AS1(p) ((const __attribute__((address_space(1))) void*)(p))
#define AS3(p) ((__attribute__((address_space(3))) void*)(p))

typedef unsigned short u16;
typedef __bf16 bf16x8 __attribute__((ext_vector_type(8)));
typedef short s16x8 __attribute__((ext_vector_type(8)));
typedef float f32x4 __attribute__((ext_vector_type(4)));
typedef unsigned short u16x4 __attribute__((ext_vector_type(4)));
typedef unsigned short u16x8v __attribute__((ext_vector_type(8)));

__device__ __forceinline__ u16 f2bf(float x) {
    unsigned u = __float_as_uint(x);
    unsigned r = (u + 0x7FFFu + ((u >> 16) & 1u)) >> 16;
    return (u16)r;
}

template <typename V8>
__device__ __forceinline__ auto mfma_sel(V8 a, V8 b, f32x4 c, int)
    -> decltype(__builtin_amdgcn_mfma_f32_16x16x32_bf16(a, b, c, 0, 0, 0))
{
    return __builtin_amdgcn_mfma_f32_16x16x32_bf16(a, b, c, 0, 0, 0);
}
template <typename V8>
__device__ __forceinline__ f32x4 mfma_sel(V8 a, V8 b, f32x4 c, long)
{
    s16x8 a2 = __builtin_bit_cast(s16x8, a);
    s16x8 b2 = __builtin_bit_cast(s16x8, b);
    return __builtin_amdgcn_mfma_f32_16x16x32_bf16(a2, b2, c, 0, 0, 0);
}
__device__ __forceinline__ f32x4 mfma16x16x32(bf16x8 a, bf16x8 b, f32x4 c)
{
    return mfma_sel(a, b, c, 0);
}

// ------- unified fp32 -> bf16 convert (x + 4 weights) + rsum zero-fill -------
__global__ __launch_bounds__(256) void cvt_all_kernel(const float* __restrict__ x,
                                                      const float* __restrict__ Wq,
                                                      const float* __restrict__ Wk,
                                                      const float* __restrict__ Wv,
                                                      const float* __restrict__ Wp,
                                                      u16* __restrict__ xb,
                                                      u16* __restrict__ Wcat,
                                                      u16* __restrict__ Wpb,
                                                      float* __restrict__ rsum,
                                                      int n4x, int n4w, int nrs)
{
    int i = blockIdx.x * 256 + threadIdx.x;
    const int total = n4x + 4 * n4w;
    if (i >= total) {
        int j = i - total;
        if (j < nrs) rsum[j] = 0.f;     // zero the row-sum accumulator each call
        return;
    }
    const float* src;
    u16* dst;
    int off;
    if (i < n4x) {
        src = x; dst = xb; off = i;
    } else {
        int j = i - n4x;
        int w = j >> 18;            // n4w == 262144 == 1<<18
        off = j & (n4w - 1);
        src = (w == 0) ? Wq : (w == 1) ? Wk : (w == 2) ? Wv : Wp;
        dst = (w == 3) ? Wpb : (Wcat + (size_t)w * n4w * 4);
    }
    float4 f = ((const float4*)src)[off];
    u16x4 o;
    o.x = f2bf(f.x); o.y = f2bf(f.y); o.z = f2bf(f.z); o.w = f2bf(f.w);
    ((u16x4*)dst)[off] = o;
}

#define MBM 128
#define MBK 64

// ============ m97-structure NT GEMM: 128x128, BK=64, 256 threads ============
// Single-buffered 32 KB static LDS, 2 barriers per K-tile. Scores (EXPOUT/
// FUSET) and PV (RDIV/PACKA). Session argmin config, validated three times
// (r16: 175.7, r20: 175.3, r21: 176.3 us).
// T2 swizzle (rule 21): linear LDS dest, inverse-XOR'd global SOURCE slot,
// XOR'd read: slot16B ^= (row&7). Conflict-free (r3..r21: 0).
// EXPOUT: scores mode — causal mask + exp(s-16) shift-softmax, P causally
//   PACKED, per-row sums via atomics. RDIV: PV epilogue divides by rsum.
// PACKA: A = packed P (block-row a: lda=128(a+1), base -8192*a*(a+1)).
// FUSET: z==4 plane transposes v (vb[8192][1024] -> vT[1024][8192], ld 8192).
template <int BIAS, int OUTBF16, int CSKIP, int CKB, int SWZ, int MW,
          int EXPOUT, int RDIV, int PACKA, int FUSET>
__global__ __launch_bounds__(256, MW)
void gemm128(const u16* __restrict__ A, const u16* __restrict__ B,
             void* __restrict__ Cv, const float* __restrict__ bias,
             void* __restrict__ C2, const float* __restrict__ bias2,
             void* __restrict__ C3, const float* __restrict__ bias3,
             float* __restrict__ rsum,
             int M, int N, int K, int lda, int ldb, int ldc,
             long long sA, long long sB, long long sC, float scale)
{
    __shared__ u16 lA[MBM * MBK];
    __shared__ u16 lB[MBM * MBK];

    if (FUSET && blockIdx.z == 4) {
        // ---- fused v-transpose: vb[8192][1024] -> vT[1024][8192] ----
        const u16* vin = (const u16*)C2;
        u16* vout = (u16*)C3;
        u16* tl = lA;                       // [64][65] scratch
        const int t = threadIdx.x;
        const int r = t >> 2, c4 = (t & 3) << 4;
        const int bid = blockIdx.y * 16 + blockIdx.x;     // 0..255
        for (int it = 0; it < 8; ++it) {
            const int tile = bid * 8 + it;                // 0..2047
            const int tc0 = (tile & 15) * 64;             // D cols
            const int tr0 = (tile >> 4) * 64;             // M rows (0..8191)
            const u16* src = vin + (size_t)(tr0 + r) * 1024 + tc0 + c4;
            u16x8v a0 = *(const u16x8v*)src;
            u16x8v a1 = *(const u16x8v*)(src + 8);
            #pragma unroll
            for (int j = 0; j < 8; ++j) {
                tl[r * 65 + c4 + j] = a0[j];
                tl[r * 65 + c4 + 8 + j] = a1[j];
            }
            __syncthreads();
            u16x8v b0, b1;
            #pragma unroll
            for (int j = 0; j < 8; ++j) {
                b0[j] = tl[(c4 + j) * 65 + r];
                b1[j] = tl[(c4 + 8 + j) * 65 + r];
            }
            u16* dst = vout + (size_t)(tc0 + r) * 8192 + tr0 + c4;  // ld = FULL M
            *(u16x8v*)dst = b0;
            *(u16x8v*)(dst + 8) = b1;
            __syncthreads();
        }
        return;
    }

    int bx = blockIdx.x, by = blockIdx.y;
    if (SWZ) {
        const int gx = gridDim.x;
        const int nwg = gx * gridDim.y;
        int id = by * gx + bx;
        id = (id & 7) * (nwg >> 3) + (id >> 3);
        bx = id % gx; by = id / gx;
    }
    if (CKB) by = gridDim.y - 1 - by;       // longest-K blocks first
    const int m0 = by * MBM;
    const int n0 = bx * MBM;
    if (CSKIP && n0 > m0 + MBM - 1) return;

    const int z = blockIdx.z;
    const int ablk = m0 >> 7;               // row-block index (packed layouts)
    long long abase = (long long)z * sA;
    int lda_e = lda;
    if (PACKA) {
        lda_e = (ablk + 1) << 7;            // == Keff
        abase -= (long long)8192 * ablk * (ablk + 1);
    }
    const u16* Ab = A + abase;
    B += (size_t)z * (size_t)sB;

    const int t = threadIdx.x;
    const int lane = t & 63;
    const int w = t >> 6;
    const int wr = w >> 1;           // 0..1 (M)
    const int wc = w & 1;            // 0..1 (N)
    const int fr = lane & 15, fg = lane >> 4;

    int Keff = K;
    if (CKB) { Keff = m0 + MBM; if (Keff > K) Keff = K; }
    const int nk = Keff / MBK;

    f32x4 acc[4][4] = {};

    for (int kt = 0; kt < nk; ++kt) {
        const int k0 = kt * MBK;
        #pragma unroll
        for (int i = 0; i < 4; ++i) {
            int c = t + i * 256;
            int row = c >> 3;
            int sl = (c & 7) ^ (row & 7);      // inverse-swizzled source slot
            __builtin_amdgcn_global_load_lds(
                AS1(Ab + (long long)(m0 + row) * lda_e + k0 + sl * 8),
                AS3(&lA[c * 8]), 16, 0, 0);
            __builtin_amdgcn_global_load_lds(
                AS1(B + (size_t)(n0 + row) * ldb + k0 + sl * 8),
                AS3(&lB[c * 8]), 16, 0, 0);
        }
        __syncthreads();                        // drains vmcnt: tile staged

        #pragma unroll
        for (int kk = 0; kk < MBK; kk += 32) {
            const int cs = (kk >> 3) + fg;      // column 16B-slot 0..7
            bf16x8 af[4], bfv[4];
            #pragma unroll
            for (int mi = 0; mi < 4; ++mi) {
                int row = wr * 64 + mi * 16 + fr;
                af[mi] = *(const bf16x8*)&lA[row * 64 + ((cs ^ (row & 7)) << 3)];
            }
            #pragma unroll
            for (int ni = 0; ni < 4; ++ni) {
                int row = wc * 64 + ni * 16 + fr;
                bfv[ni] = *(const bf16x8*)&lB[row * 64 + ((cs ^ (row & 7)) << 3)];
            }
            __builtin_amdgcn_s_setprio(1);
            #pragma unroll
            for (int mi = 0; mi < 4; ++mi)
                #pragma unroll
                for (int ni = 0; ni < 4; ++ni)
                    acc[mi][ni] = mfma16x16x32(af[mi], bfv[ni], acc[mi][ni]);
            __builtin_amdgcn_s_setprio(0);
        }
        __syncthreads();                        // reads done before next stage
    }

    // ---- epilogue: C/D layout col=lane&15, row=(lane>>4)*4+reg ----
    if (EXPOUT) {
        // scores: causal mask + exp(s-16); PACKED C; per-row sum atomics
        const int ldcp = (ablk + 1) << 7;
        u16* Cp = (u16*)Cv + ((long long)z * sC - (long long)8192 * ablk * (ablk + 1));
        float prs[4][4];
        #pragma unroll
        for (int mi = 0; mi < 4; ++mi)
            #pragma unroll
            for (int j = 0; j < 4; ++j) prs[mi][j] = 0.f;
        #pragma unroll
        for (int mi = 0; mi < 4; ++mi) {
            int row0 = m0 + wr * 64 + mi * 16 + fg * 4;
            #pragma unroll
            for (int ni = 0; ni < 4; ++ni) {
                int col = n0 + wc * 64 + ni * 16 + fr;
                #pragma unroll
                for (int j = 0; j < 4; ++j) {
                    int row = row0 + j;
                    float p = (col <= row) ? __expf(acc[mi][ni][j] - 16.f) : 0.f;
                    Cp[(long long)row * ldcp + col] = f2bf(p);
                    prs[mi][j] += p;
                }
            }
        }
        #pragma unroll
        for (int mi = 0; mi < 4; ++mi) {
            #pragma unroll
            for (int j = 0; j < 4; ++j) {
                float s = prs[mi][j];
                s += __shfl_xor(s, 1); s += __shfl_xor(s, 2);
                s += __shfl_xor(s, 4); s += __shfl_xor(s, 8);
                if (fr == 0)
                    atomicAdd(&rsum[(size_t)z * M + m0 + wr * 64 + mi * 16 + fg * 4 + j], s);
            }
        }
        return;
    }

    #pragma unroll
    for (int mi = 0; mi < 4; ++mi) {
        int row0 = m0 + wr * 64 + mi * 16 + fg * 4;
        float invr[4];
        if (RDIV) {
            #pragma unroll
            for (int j = 0; j < 4; ++j)
                invr[j] = 1.f / rsum[(size_t)z * M + row0 + j];
        }
        #pragma unroll
        for (int ni = 0; ni < 4; ++ni) {
            int col = n0 + wc * 64 + ni * 16 + fr;
            float bval = (BIAS == 1) ? bias[col] : 0.f;
            #pragma unroll
            for (int j = 0; j < 4; ++j) {
                float v = RDIV ? acc[mi][ni][j] * invr[j]
                               : (acc[mi][ni][j] + bval) * scale;
                size_t off = (size_t)z * (size_t)sC + (size_t)(row0 + j) * ldc + col;
                if (OUTBF16) ((u16*)Cv)[off] = f2bf(v);
                else         ((float*)Cv)[off] = v;
            }
        }
    }
}

// ========== pipelined NT GEMM: counted-vmcnt, A-triple / B-double buffer =====
// 128x128, BK=64, 256 threads, 80 KB dynamic LDS -> 2 blocks/CU.
// QKV (BIAS=3) + proj: best-total config (argmin r16/r20/r21).
// Race proof: writes target bufA[(t+2)%3]==bufA[(t-1)%3], bufB[(t+1)&1]==
// bufB[(t-1)&1], whose ds_reads completed (compiler lgkmcnt before MFMA)
// before barrier(t-1); every wave issues iter-t writes only after that
// barrier. Reads at iter t confirmed by every wave's vmcnt(4) at t-1.
#define PLDS 81920

template <int BIAS, int OUTBF16>
__global__ __launch_bounds__(256, 2)
void gemm128p(const u16* __restrict__ A, const u16* __restrict__ B,
              void* __restrict__ Cv, const float* __restrict__ bias,
              void* __restrict__ C2, const float* __restrict__ bias2,
              void* __restrict__ C3, const float* __restrict__ bias3,
              int M, int N, int K, int lda, int ldb, int ldc, float scale)
{
    extern __shared__ char smem[];

    // bijective XCD swizzle (nwg % 8 == 0 at both call sites)
    const int gx = gridDim.x;
    const int nwg = gx * gridDim.y;
    int id = blockIdx.y * gx + blockIdx.x;
    id = (id & 7) * (nwg >> 3) + (id >> 3);
    const int bx = id % gx;
    const int by = id / gx;
    const int m0 = by * MBM;
    const int n0 = bx * MBM;

    const int t = threadIdx.x;
    const int lane = t & 63;
    const int w = t >> 6;
    const int wr = w >> 1, wc = w & 1;
    const int fr = lane & 15, fg = lane >> 4;

    const int nk = K / MBK;

    char* const aB = smem;           // 3 x 16 KB A buffers
    char* const bB = smem + 49152;   // 2 x 16 KB B buffers

    auto STA = [&](int kt, char* dst) {
        const int k0 = kt * MBK;
        #pragma unroll
        for (int i = 0; i < 4; ++i) {
            int c = t + i * 256;
            int row = c >> 3;
            int sl = (c & 7) ^ (row & 7);
            __builtin_amdgcn_global_load_lds(
                AS1(A + (size_t)(m0 + row) * lda + k0 + sl * 8),
                AS3(dst + c * 16), 16, 0, 0);
        }
    };
    auto STB = [&](int kt, char* dst) {
        const int k0 = kt * MBK;
        #pragma unroll
        for (int i = 0; i < 4; ++i) {
            int c = t + i * 256;
            int row = c >> 3;
            int sl = (c & 7) ^ (row & 7);
            __builtin_amdgcn_global_load_lds(
                AS1(B + (size_t)(n0 + row) * ldb + k0 + sl * 8),
                AS3(dst + c * 16), 16, 0, 0);
        }
    };

    f32x4 acc[4][4] = {};

    // prologue
    STA(0, aB);
    STB(0, bB);
    if (nk > 1) {
        STA(1, aB + 16384);
        asm volatile("s_waitcnt vmcnt(4)" ::: "memory");
    } else {
        asm volatile("s_waitcnt vmcnt(0)" ::: "memory");
    }
    __builtin_amdgcn_s_barrier();

    int ca = 0;                      // A buffer holding tile kt
    for (int kt = 0; kt < nk; ++kt) {
        if (kt + 1 < nk) STB(kt + 1, bB + ((kt + 1) & 1) * 16384);
        int pa = ca + 2; if (pa >= 3) pa -= 3;
        if (kt + 2 < nk) STA(kt + 2, aB + pa * 16384);

        const char* la = aB + ca * 16384;
        const char* lb = bB + (kt & 1) * 16384;
        #pragma unroll
        for (int kk = 0; kk < MBK; kk += 32) {
            const int cs = (kk >> 3) + fg;
            bf16x8 af[4], bfv[4];
            #pragma unroll
            for (int mi = 0; mi < 4; ++mi) {
                int row = wr * 64 + mi * 16 + fr;
                af[mi] = *(const bf16x8*)(la + row * 128 + ((cs ^ (row & 7)) << 4));
            }
            #pragma unroll
            for (int ni = 0; ni < 4; ++ni) {
                int row = wc * 64 + ni * 16 + fr;
                bfv[ni] = *(const bf16x8*)(lb + row * 128 + ((cs ^ (row & 7)) << 4));
            }
            __builtin_amdgcn_s_setprio(1);
            #pragma unroll
            for (int mi = 0; mi < 4; ++mi)
                #pragma unroll
                for (int ni = 0; ni < 4; ++ni)
                    acc[mi][ni] = mfma16x16x32(af[mi], bfv[ni], acc[mi][ni]);
            __builtin_amdgcn_s_setprio(0);
        }

        if (kt + 2 < nk)      asm volatile("s_waitcnt vmcnt(4)" ::: "memory");
        else if (kt + 1 < nk) asm volatile("s_waitcnt vmcnt(0)" ::: "memory");
        if (kt + 1 < nk) __builtin_amdgcn_s_barrier();
        ++ca; if (ca >= 3) ca = 0;
    }

    // ---- epilogue: C/D layout col=lane&15, row=(lane>>4)*4+reg ----
    #pragma unroll
    for (int mi = 0; mi < 4; ++mi) {
        int row0 = m0 + wr * 64 + mi * 16 + fg * 4;
        #pragma unroll
        for (int ni = 0; ni < 4; ++ni) {
            int col = n0 + wc * 64 + ni * 16 + fr;
            if (BIAS == 3) {
                int seg = col >> 10;
                int ccol = col & 1023;
                u16* dst = (seg == 0) ? (u16*)Cv : (seg == 1) ? (u16*)C2 : (u16*)C3;
                float b = ((seg == 0) ? bias : (seg == 1) ? bias2 : bias3)[ccol];
                float sc_ = (seg == 0) ? scale : 1.f;
                #pragma unroll
                for (int j = 0; j < 4; ++j)
                    dst[(size_t)(row0 + j) * 1024 + ccol] =
                        f2bf((acc[mi][ni][j] + b) * sc_);
            } else {
                float bval = (BIAS == 1) ? bias[col] : 0.f;
                #pragma unroll
                for (int j = 0; j < 4; ++j) {
                    float v = (acc[mi][ni][j] + bval) * scale;
                    size_t off = (size_t)(row0 + j) * ldc + col;
                    if (OUTBF16) ((u16*)Cv)[off] = f2bf(v);
                    else         ((float*)Cv)[off] = v;
                }
            }
        }
    }
}

// ---------------- host launcher ----------------
// ws layout (87.1 MB; ws >= 92.3 MB deduced from r1):
//   [xb 16.78M | Wpb 2.1M | qb 16.78M | kb 16.78M | rsum 32K | vb 16.78M |
//    scp 17.83M (packed P; first 6.29M overlaid by Wcat, dead after QKV)]
//   vTb aliases xb (x dead after QKV; written by fused transpose during the
//   scores launch). attnb aliases kb (kb dead after scores).
extern "C" void kernel_launch(void* const* d_in, const int* in_sizes, int n_in,
                              void* d_out, int out_size, void* d_ws, size_t ws_size,
                              hipStream_t stream)
{
    (void)in_sizes; (void)n_in; (void)out_size; (void)ws_size;
    const float* x  = (const float*)d_in[0];
    const float* Wq = (const float*)d_in[1];
    const float* bq = (const float*)d_in[2];
    const float* Wk = (const float*)d_in[3];
    const float* bk = (const float*)d_in[4];
    const float* Wv = (const float*)d_in[5];
    const float* bv = (const float*)d_in[6];
    const float* Wp = (const float*)d_in[7];
    const float* bp = (const float*)d_in[8];

    const int D = 1024, S = 2048, B = 4;
    const int M = B * S; // 8192
    const long long sP = 16384LL * 136;     // packed P elems per batch

    char* p = (char*)d_ws;
    u16* xb    = (u16*)p; p += (size_t)M * D * 2;      // 16.78M
    u16* Wpb   = (u16*)p; p += (size_t)D * D * 2;      // 2.1M
    u16* qb    = (u16*)p; p += (size_t)M * D * 2;      // 16.78M
    u16* kb    = (u16*)p; p += (size_t)M * D * 2;      // 16.78M
    float* rsum = (float*)p; p += (size_t)B * S * 4;   // 32K
    u16* vb    = (u16*)p; p += (size_t)M * D * 2;      // 16.78M
    u16* scp   = (u16*)p;                              // packed P 17.83M
    u16* Wcat  = scp;                                  // overlay: dead after QKV
    u16* vTb   = xb;                                   // alias: x dead after QKV
    u16* attnb = kb;                                   // alias: kb dead after scores

    const int n4x = M * D / 4;      // 2097152
    const int n4w = D * D / 4;      // 262144
    const int nrs = B * S;          // 8192

    hipFuncSetAttribute((const void*)gemm128p<3, 1>,
                        hipFuncAttributeMaxDynamicSharedMemorySize, PLDS);
    hipFuncSetAttribute((const void*)gemm128p<1, 0>,
                        hipFuncAttributeMaxDynamicSharedMemorySize, PLDS);

    // fp32 -> bf16 (x + weights) + rsum zero-fill, one launch
    cvt_all_kernel<<<(n4x + 4 * n4w + nrs + 255) / 256, 256, 0, stream>>>(
        x, Wq, Wk, Wv, Wp, xb, Wcat, Wpb, rsum, n4x, n4w, nrs);

    // fused QKV: [q|k|v] = x Wcat^T + biases (q scaled); PIPELINED kernel
    gemm128p<3, 1><<<dim3(3 * D / MBM, M / MBM), 256, PLDS, stream>>>(
        xb, Wcat, qb, bq, kb, bk, vb, bv,
        M, 3 * D, D, D, D, D, 0.03125f);

    // scores -> packed P = exp(s-16), causal mask, row-sum atomics (EXPOUT);
    // z==4 plane: fused v-transpose (vb -> vTb) riding idle causal-skip slots
    gemm128<0, 1, 1, 0, 0, 4, 1, 0, 0, 1><<<dim3(S / MBM, S / MBM, B + 1), 256, 0, stream>>>(
        qb, kb, scp, nullptr, vb, nullptr, vTb, nullptr, rsum,
        S, S, D, D, D, 0,
        (long long)S * D, (long long)S * D, sP, 1.0f);

    // attn_out = (P v) / rsum[row]  (RDIV; PACKA; K causally bounded)
    gemm128<0, 1, 0, 1, 0, 4, 0, 1, 1, 0><<<dim3(D / MBM, S / MBM, B), 256, 0, stream>>>(
        scp, vTb, attnb, nullptr, nullptr, nullptr, nullptr, nullptr, rsum,
        S, D, S, 0, M, D,
        sP, (long long)S, (long long)S * D, 1.0f);

    // out = attn_out Wp^T + bp  (fp32 output); PIPELINED gemm128p
    gemm128p<1, 0><<<dim3(D / MBM, M / MBM), 256, PLDS, stream>>>(
        attnb, Wpb, d_out, bp, nullptr, nullptr, nullptr, nullptr,
        M, D, D, D, D, D, 1.0f);
}